// Round 1
// baseline (357.453 us; speedup 1.0000x reference)
//
#include <hip/hip_runtime.h>

// Fused DigitConvolutionalModel:
//   conv3x3(valid) on 28x28 -> 676 feats -> fc1(100)+ReLU -> fc2(10)
// One block (256 thr / 4 waves) handles 32 images.
//   Phase 1: conv in fp32 from global x, write bf16 A-tile to LDS [32][712]
//   Phase 2: mfma_f32_32x32x16_bf16, wave w = neuron tile w (N=100 -> 4 tiles)
//   Phase 3: bias+relu -> LDS hbuf (fp32), fc2 in fp32 VALU, store out.

typedef short s16x8 __attribute__((ext_vector_type(8)));   // 8 bf16 in 4 VGPRs
typedef float f32x16 __attribute__((ext_vector_type(16))); // MFMA 32x32 acc

#define BM   32     // images per block
#define CSTR 712    // cbuf row stride (bf16 elems): 1424 B -> dword stride 356 (= 4 mod 8, minimal bank aliasing for b128)
#define HSTR 132    // hbuf row stride (floats)
#define KPAD 688    // K padded to 43*16

// fp32 -> bf16 round-to-nearest-even (manual, no header-type ambiguity)
__device__ __forceinline__ unsigned short f2bf(float f) {
    unsigned int u = __builtin_bit_cast(unsigned int, f);
    u = (u + 0x7fffu + ((u >> 16) & 1u)) >> 16;
    return (unsigned short)u;
}

extern "C" __global__ void __launch_bounds__(256, 3)
digit_model_fused(const float* __restrict__ x,
                  const float* __restrict__ cw9,
                  const float* __restrict__ W1,
                  const float* __restrict__ b1,
                  const float* __restrict__ W2,
                  const float* __restrict__ b2,
                  float* __restrict__ out)
{
    __shared__ __align__(16) unsigned char smem[BM * CSTR * 2]; // 45568 B
    unsigned short* cbuf = (unsigned short*)smem;   // phase 1/2: bf16 conv tile
    float*          hbuf = (float*)smem;            // phase 3: fp32 h tile (aliased)

    const int tid  = threadIdx.x;
    const int lane = tid & 63;
    const int wv   = tid >> 6;      // wave id = neuron tile
    const int half = lane >> 5;     // k-half within MFMA chunk
    const int ln   = lane & 31;
    const int m0   = blockIdx.x * BM;

    // conv weights -> registers
    float cw[9];
    #pragma unroll
    for (int i = 0; i < 9; ++i) cw[i] = cw9[i];

    // zero K-pad region [676, 712) of every cbuf row (36 ushorts = 18 uints/row)
    for (int p = tid; p < BM * 18; p += 256) {
        int mi = p / 18, q = p - mi * 18;
        *(unsigned int*)(cbuf + mi * CSTR + 676 + q * 2) = 0u;
    }

    // ---------------- Phase 1: conv (fp32), 32 imgs x 26 rows = 832 tasks ----
    for (int task = tid; task < BM * 26; task += 256) {
        int mi = task / 26, r = task - mi * 26;
        const float* ip = x + (size_t)(m0 + mi) * 784 + r * 28;
        float acc[26];
        #pragma unroll
        for (int c = 0; c < 26; ++c) acc[c] = 0.f;
        #pragma unroll
        for (int dr = 0; dr < 3; ++dr) {
            float rowv[28];
            const float4* rp = (const float4*)(ip + dr * 28); // 16B aligned
            #pragma unroll
            for (int q = 0; q < 7; ++q) {
                float4 t = rp[q];
                rowv[q*4+0] = t.x; rowv[q*4+1] = t.y;
                rowv[q*4+2] = t.z; rowv[q*4+3] = t.w;
            }
            #pragma unroll
            for (int dc = 0; dc < 3; ++dc) {
                float w = cw[dr*3+dc];
                #pragma unroll
                for (int c = 0; c < 26; ++c) acc[c] = fmaf(rowv[c+dc], w, acc[c]);
            }
        }
        unsigned short* dst = cbuf + mi * CSTR + r * 26; // 4B aligned (52*r)
        #pragma unroll
        for (int c = 0; c < 26; c += 2) {
            unsigned int u = (unsigned int)f2bf(acc[c])
                           | ((unsigned int)f2bf(acc[c+1]) << 16);
            *(unsigned int*)(dst + c) = u;
        }
    }
    __syncthreads();

    // ---------------- Phase 2: h = conv @ W1^T via MFMA 32x32x16 bf16 -------
    // A: lane holds A[m=ln][k=half*8+j]; B: lane holds B[k=half*8+j][n=ln]
    const int n = wv * 32 + ln;                 // global neuron index (0..127)
    const bool nvalid = (n < 100);
    f32x16 acc;
    #pragma unroll
    for (int i = 0; i < 16; ++i) acc[i] = 0.f;

    const unsigned short* arow = cbuf + ln * CSTR + half * 8;
    const float* wrow = W1 + (size_t)(nvalid ? n : 0) * 676;

    for (int kc = 0; kc < 43; ++kc) {
        const int k0 = kc * 16 + half * 8;
        uint4 araw = *(const uint4*)(arow + kc * 16);     // ds_read_b128
        s16x8 a = __builtin_bit_cast(s16x8, araw);

        s16x8 b;
        if (nvalid && (k0 + 8 <= 676)) {
            float4 p = *(const float4*)(wrow + k0);       // 16B aligned
            float4 q = *(const float4*)(wrow + k0 + 4);
            b[0] = (short)f2bf(p.x); b[1] = (short)f2bf(p.y);
            b[2] = (short)f2bf(p.z); b[3] = (short)f2bf(p.w);
            b[4] = (short)f2bf(q.x); b[5] = (short)f2bf(q.y);
            b[6] = (short)f2bf(q.z); b[7] = (short)f2bf(q.w);
        } else {
            #pragma unroll
            for (int j = 0; j < 8; ++j) {
                float v = (nvalid && (k0 + j) < 676) ? wrow[k0 + j] : 0.f;
                b[j] = (short)f2bf(v);
            }
        }
        acc = __builtin_amdgcn_mfma_f32_32x32x16_bf16(a, b, acc, 0, 0, 0);
    }
    __syncthreads();   // all cbuf reads done; smem can be reused as hbuf

    // ---------------- Phase 3a: bias + relu -> hbuf -------------------------
    // C/D layout (verified): col = lane&31, row = (reg&3) + 8*(reg>>2) + 4*(lane>>5)
    const float bias1 = nvalid ? b1[n] : 0.f;
    #pragma unroll
    for (int r = 0; r < 16; ++r) {
        int row = (r & 3) + 8 * (r >> 2) + 4 * half;
        float v = acc[r] + bias1;
        v = v > 0.f ? v : 0.f;
        hbuf[row * HSTR + n] = v;   // n<100 real, n>=100 writes 0 (never read)
    }
    __syncthreads();

    // ---------------- Phase 3b: fc2 (fp32 VALU) + store ---------------------
    for (int p = tid; p < BM * 10; p += 256) {
        int mi = p / 10, o = p - mi * 10;
        const float4* hv = (const float4*)(hbuf + mi * HSTR);
        const float4* w2 = (const float4*)(W2 + o * 100);
        float s = b2[o];
        #pragma unroll
        for (int q = 0; q < 25; ++q) {
            float4 h4 = hv[q], w4 = w2[q];
            s += h4.x*w4.x + h4.y*w4.y + h4.z*w4.z + h4.w*w4.w;
        }
        out[(size_t)(m0 + mi) * 10 + o] = s;
    }
}

extern "C" void kernel_launch(void* const* d_in, const int* in_sizes, int n_in,
                              void* d_out, int out_size, void* d_ws, size_t ws_size,
                              hipStream_t stream) {
    const float* x  = (const float*)d_in[0];
    const float* cw = (const float*)d_in[1];
    const float* W1 = (const float*)d_in[2];
    const float* b1 = (const float*)d_in[3];
    const float* W2 = (const float*)d_in[4];
    const float* b2 = (const float*)d_in[5];
    float* out = (float*)d_out;

    const int B = in_sizes[0] / 784;           // 65536
    dim3 grid(B / BM), block(256);
    hipLaunchKernelGGL(digit_model_fused, grid, block, 0, stream,
                       x, cw, W1, b1, W2, b2, out);
}

// Round 2
// 348.232 us; speedup vs baseline: 1.0265x; 1.0265x over previous
//
#include <hip/hip_runtime.h>

// Fused DigitConvolutionalModel, R2:
//   conv3x3(valid) 28x28 -> 676 -> fc1(100)+ReLU (bf16 MFMA) -> fc2(10)
// prep_w1: swizzles W1(fp32) + b1 into MFMA B-fragment bf16 layout in d_ws,
//          with bias folded in at k==676 (A supplies 1.0 there via K-pad).
// main:    512 thr / 8 waves per block, 32 images. Wave pair (t, t+4) splits
//          K (21/22 chunks) for tile t; partials reduced through LDS.

typedef short  s16x8  __attribute__((ext_vector_type(8)));   // 8 bf16
typedef float  f32x16 __attribute__((ext_vector_type(16)));  // 32x32 acc

#define BM   32     // images per block
#define CSTR 712    // cbuf row stride in bf16 (1424 B)
#define HSTR 132    // hbuf row stride in floats
#define NT   4      // n-tiles of 32 (N=100 -> 4)
#define KC   43     // k-chunks of 16 (K=676 -> pad 688)

__device__ __forceinline__ unsigned short f2bf(float f) {
    unsigned int u = __builtin_bit_cast(unsigned int, f);
    u = (u + 0x7fffu + ((u >> 16) & 1u)) >> 16;
    return (unsigned short)u;
}

// ---- prep: W1 [100][676] fp32 -> bw [t][kc][lane][8] bf16 (B-fragment) ----
// lane ln,half holds B[k = kc*16 + half*8 + j][n = t*32 + ln]; k==676 -> b1[n]
extern "C" __global__ void __launch_bounds__(256)
prep_w1(const float* __restrict__ W1, const float* __restrict__ b1,
        unsigned short* __restrict__ bw)
{
    int id = blockIdx.x * 256 + threadIdx.x;      // one thread per (t,kc,lane)
    if (id >= NT * KC * 64) return;
    int lane = id & 63;
    int kc   = (id >> 6) % KC;
    int t    = id / (KC * 64);
    int n    = t * 32 + (lane & 31);
    int k0   = kc * 16 + (lane >> 5) * 8;
    unsigned short v[8];
#pragma unroll
    for (int j = 0; j < 8; ++j) {
        int k = k0 + j;
        float f = 0.f;
        if (n < 100) {
            if (k < 676)       f = W1[(size_t)n * 676 + k];
            else if (k == 676) f = b1[n];        // bias folded into GEMM
        }
        v[j] = f2bf(f);
    }
    *(uint4*)(bw + (size_t)id * 8) = *(const uint4*)v;
}

// ---------------------------- main kernel ----------------------------------
extern "C" __global__ void __launch_bounds__(512, 6)
digit_model_fused(const float* __restrict__ x,
                  const float* __restrict__ cw9,
                  const unsigned short* __restrict__ bw,
                  const float* __restrict__ W2,
                  const float* __restrict__ b2,
                  float* __restrict__ out)
{
    __shared__ __align__(16) unsigned char smem[BM * CSTR * 2]; // 45568 B
    unsigned short* cbuf = (unsigned short*)smem;       // phase 1/2: bf16 A
    float* pbuf = (float*)smem;                         // phase 3: partials (16 KB)
    float* hbuf = (float*)(smem + 16384);               // phase 3: h (16.9 KB)

    const int tid  = threadIdx.x;
    const int lane = tid & 63;
    const int wv   = tid >> 6;        // 0..7
    const int t    = wv & 3;          // n-tile
    const int half = lane >> 5;
    const int ln   = lane & 31;
    const int m0   = blockIdx.x * BM;

    float cw[9];
#pragma unroll
    for (int i = 0; i < 9; ++i) cw[i] = cw9[i];

    // K-pad [676,712): zeros, except A[mi][676] = 1.0 (bias multiplicand)
    for (int p = tid; p < BM * 18; p += 512) {
        int mi = p / 18, q = p - mi * 18;
        *(unsigned int*)(cbuf + mi * CSTR + 676 + q * 2) = (q == 0) ? 0x3F80u : 0u;
    }

    // ---------------- Phase 1: conv fp32 -> bf16 A-tile in LDS --------------
    for (int task = tid; task < BM * 26; task += 512) {
        int mi = task / 26, r = task - mi * 26;
        const float* ip = x + (size_t)(m0 + mi) * 784 + r * 28;
        float acc[26];
#pragma unroll
        for (int c = 0; c < 26; ++c) acc[c] = 0.f;
#pragma unroll
        for (int dr = 0; dr < 3; ++dr) {
            float rowv[28];
            const float4* rp = (const float4*)(ip + dr * 28);
#pragma unroll
            for (int q = 0; q < 7; ++q) {
                float4 v = rp[q];
                rowv[q*4+0] = v.x; rowv[q*4+1] = v.y;
                rowv[q*4+2] = v.z; rowv[q*4+3] = v.w;
            }
#pragma unroll
            for (int dc = 0; dc < 3; ++dc) {
                float w = cw[dr*3+dc];
#pragma unroll
                for (int c = 0; c < 26; ++c) acc[c] = fmaf(rowv[c+dc], w, acc[c]);
            }
        }
        unsigned short* dst = cbuf + mi * CSTR + r * 26;
#pragma unroll
        for (int c = 0; c < 26; c += 2) {
            unsigned int u = (unsigned int)f2bf(acc[c])
                           | ((unsigned int)f2bf(acc[c+1]) << 16);
            *(unsigned int*)(dst + c) = u;
        }
    }
    __syncthreads();

    // ---------------- Phase 2: MFMA, K split across wave pairs --------------
    // wave wv<4: kc 0..20 ; wave wv>=4: kc 21..42 (includes bias chunk)
    const int kbeg = (wv < 4) ? 0 : 21;
    const int kend = (wv < 4) ? 21 : KC;

    f32x16 acc;
#pragma unroll
    for (int i = 0; i < 16; ++i) acc[i] = 0.f;

    const unsigned short* arow = cbuf + ln * CSTR + half * 8;
    const uint4* bwv = (const uint4*)bw;

    uint4 araw = *(const uint4*)(arow + kbeg * 16);            // ds_read_b128
    uint4 braw = bwv[(t * KC + kbeg) * 64 + lane];             // coalesced 1KB/wave
    for (int kc = kbeg; kc < kend; ++kc) {
        int kn = (kc + 1 < kend) ? kc + 1 : kc;                // clamped prefetch
        uint4 na = *(const uint4*)(arow + kn * 16);
        uint4 nb = bwv[(t * KC + kn) * 64 + lane];
        acc = __builtin_amdgcn_mfma_f32_32x32x16_bf16(
                  __builtin_bit_cast(s16x8, araw),
                  __builtin_bit_cast(s16x8, braw), acc, 0, 0, 0);
        araw = na; braw = nb;
    }
    __syncthreads();          // all cbuf reads done; smem reusable

    // ---------------- Phase 3a: reduce partials, bias(already in)+relu ------
    // C/D layout: col = ln, row = (r&3) + 8*(r>>2) + 4*half
    if (wv >= 4) {
#pragma unroll
        for (int r = 0; r < 16; ++r) {
            int row = (r & 3) + 8 * (r >> 2) + 4 * half;
            pbuf[t * 1024 + row * 32 + ln] = acc[r];
        }
    }
    __syncthreads();
    if (wv < 4) {
#pragma unroll
        for (int r = 0; r < 16; ++r) {
            int row = (r & 3) + 8 * (r >> 2) + 4 * half;
            float v = acc[r] + pbuf[t * 1024 + row * 32 + ln];
            v = v > 0.f ? v : 0.f;
            hbuf[row * HSTR + t * 32 + ln] = v;   // cols >=100 are 0, never read
        }
    }
    __syncthreads();

    // ---------------- Phase 3b: fc2 (fp32 VALU) + store ---------------------
    for (int p = tid; p < BM * 10; p += 512) {
        int mi = p / 10, o = p - mi * 10;
        const float4* hv = (const float4*)(hbuf + mi * HSTR);
        const float4* w2 = (const float4*)(W2 + (size_t)o * 100);
        float s = b2[o];
#pragma unroll
        for (int q = 0; q < 25; ++q) {
            float4 h4 = hv[q], w4 = w2[q];
            s += h4.x*w4.x + h4.y*w4.y + h4.z*w4.z + h4.w*w4.w;
        }
        out[(size_t)(m0 + mi) * 10 + o] = s;
    }
}

extern "C" void kernel_launch(void* const* d_in, const int* in_sizes, int n_in,
                              void* d_out, int out_size, void* d_ws, size_t ws_size,
                              hipStream_t stream) {
    const float* x  = (const float*)d_in[0];
    const float* cw = (const float*)d_in[1];
    const float* W1 = (const float*)d_in[2];
    const float* b1 = (const float*)d_in[3];
    const float* W2 = (const float*)d_in[4];
    const float* b2 = (const float*)d_in[5];
    float* out = (float*)d_out;
    unsigned short* bw = (unsigned short*)d_ws;    // 176,128 B used

    const int B = in_sizes[0] / 784;               // 65536

    hipLaunchKernelGGL(prep_w1, dim3((NT * KC * 64 + 255) / 256), dim3(256),
                       0, stream, W1, b1, bw);
    hipLaunchKernelGGL(digit_model_fused, dim3(B / BM), dim3(512), 0, stream,
                       x, cw, bw, W2, b2, out);
}

// Round 3
// 327.812 us; speedup vs baseline: 1.0904x; 1.0623x over previous
//
#include <hip/hip_runtime.h>

// Fused DigitConvolutionalModel, R3:
//   conv3x3(valid) 28x28 -> 676 -> fc1(100)+ReLU (bf16 MFMA 16x16x32) -> fc2(10)
// BM=16 images/block, 256 thr (4 waves), LDS 22.8 KB -> 7 blocks/CU.
// prep_w1 swizzles W1+b1 into B-fragment bf16 layout (bias folded at k==676,
// A supplies 1.0 there via K-pad). Conv uses half-row tasks to keep VGPRs low
// (R2's spill disaster: launch_bounds cap 85 vs ~84 live -> 54 MB scratch).

typedef short  s16x8 __attribute__((ext_vector_type(8)));   // 8 bf16
typedef float  f32x4 __attribute__((ext_vector_type(4)));   // 16x16 acc

#define BM   16     // images per block
#define CSTR 712    // cbuf row stride in bf16 (1424 B; dword stride 356 = 4 mod 32 -> 2-way max)
#define HSTR 132    // hbuf row stride in floats
#define NT   8      // n-tiles of 16 (N=100 -> 7 live + 1 zero tile)
#define KC   22     // k-chunks of 32 (K=676 -> pad 704)

__device__ __forceinline__ unsigned short f2bf(float f) {
    unsigned int u = __builtin_bit_cast(unsigned int, f);
    u = (u + 0x7fffu + ((u >> 16) & 1u)) >> 16;
    return (unsigned short)u;
}

// ---- prep: W1 [100][676] fp32 -> bw [t][kc][lane][8] bf16 (B-fragment) ----
// lane (n=lane&15, q=lane>>4) holds B[k = kc*32 + q*8 + j][n = t*16 + (lane&15)]
// k==676 -> b1[n] (bias row); n>=100 or k>676 -> 0.
extern "C" __global__ void __launch_bounds__(256)
prep_w1(const float* __restrict__ W1, const float* __restrict__ b1,
        unsigned short* __restrict__ bw)
{
    int id = blockIdx.x * 256 + threadIdx.x;
    if (id >= NT * KC * 64) return;
    int lane = id & 63;
    int kc   = (id >> 6) % KC;
    int t    = id / (KC * 64);
    int n    = t * 16 + (lane & 15);
    int k0   = kc * 32 + (lane >> 4) * 8;
    unsigned short v[8];
#pragma unroll
    for (int j = 0; j < 8; ++j) {
        int k = k0 + j;
        float f = 0.f;
        if (n < 100) {
            if (k < 676)       f = W1[(size_t)n * 676 + k];
            else if (k == 676) f = b1[n];
        }
        v[j] = f2bf(f);
    }
    *(uint4*)(bw + (size_t)id * 8) = *(const uint4*)v;
}

// ---------------------------- main kernel ----------------------------------
extern "C" __global__ void __launch_bounds__(256, 6)
digit_model_fused(const float* __restrict__ x,
                  const float* __restrict__ cw9,
                  const unsigned short* __restrict__ bw,
                  const float* __restrict__ W2,
                  const float* __restrict__ b2,
                  float* __restrict__ out)
{
    __shared__ __align__(16) unsigned char smem[BM * CSTR * 2]; // 22784 B
    unsigned short* cbuf = (unsigned short*)smem;   // phase 1/2: bf16 A-tile
    float*          hbuf = (float*)smem;            // phase 3: fp32 h (aliased)

    const int tid  = threadIdx.x;
    const int lane = tid & 63;
    const int wv   = tid >> 6;       // 0..3
    const int q    = lane >> 4;      // k-quarter
    const int mn   = lane & 15;      // m (A rows / C cols)
    const int m0   = blockIdx.x * BM;

    float cw[9];
#pragma unroll
    for (int i = 0; i < 9; ++i) cw[i] = cw9[i];

    // K-pad [676,712): zeros except A[mi][676] = 1.0 (bias multiplicand)
    for (int p = tid; p < BM * 18; p += 256) {
        int mi = p / 18, qq = p - mi * 18;
        *(unsigned int*)(cbuf + mi * CSTR + 676 + qq * 2) = (qq == 0) ? 0x3F80u : 0u;
    }

    // -------- Phase 1: conv fp32, half-row tasks (13 outputs) ---------------
    // task -> (mi, r, h): image mi, output row r, half h (cols h*13..h*13+12)
    for (int task = tid; task < BM * 52; task += 256) {
        int mi = task / 52, rh = task - mi * 52, r = rh >> 1, h = rh & 1;
        const float* ip = x + (size_t)(m0 + mi) * 784 + r * 28 + h * 12;
        float acc[13];
#pragma unroll
        for (int c = 0; c < 13; ++c) acc[c] = 0.f;
#pragma unroll
        for (int dr = 0; dr < 3; ++dr) {
            float rowv[16];
            const float4* rp = (const float4*)(ip + dr * 28);   // 16B aligned
#pragma unroll
            for (int g = 0; g < 4; ++g) {
                float4 v = rp[g];
                rowv[g*4+0] = v.x; rowv[g*4+1] = v.y;
                rowv[g*4+2] = v.z; rowv[g*4+3] = v.w;
            }
#pragma unroll
            for (int dc = 0; dc < 3; ++dc) {
                float w = cw[dr*3+dc];
#pragma unroll
                for (int c = 0; c < 13; ++c)
                    acc[c] = fmaf(rowv[c + dc + h], w, acc[c]);
            }
        }
        unsigned short* dst = cbuf + mi * CSTR + r * 26 + h * 13;
        if (h == 0) {
#pragma unroll
            for (int c = 0; c < 12; c += 2)
                *(unsigned int*)(dst + c) =
                    (unsigned int)f2bf(acc[c]) | ((unsigned int)f2bf(acc[c+1]) << 16);
            dst[12] = f2bf(acc[12]);
        } else {
            dst[0] = f2bf(acc[0]);
#pragma unroll
            for (int c = 1; c < 13; c += 2)
                *(unsigned int*)(dst + c) =
                    (unsigned int)f2bf(acc[c]) | ((unsigned int)f2bf(acc[c+1]) << 16);
        }
    }
    __syncthreads();

    // -------- Phase 2: h = A @ W1^T via MFMA 16x16x32, 2 n-tiles/wave -------
    f32x4 acc0, acc1;
#pragma unroll
    for (int i = 0; i < 4; ++i) { acc0[i] = 0.f; acc1[i] = 0.f; }

    const unsigned short* arow = cbuf + mn * CSTR + q * 8;
    const uint4* bwv = (const uint4*)bw;
    const int t0 = wv, t1 = wv + 4;

    uint4 a  = *(const uint4*)(arow);                 // ds_read_b128
    uint4 b0 = bwv[(t0 * KC) * 64 + lane];            // coalesced 1KB/wave
    uint4 b1 = bwv[(t1 * KC) * 64 + lane];
    for (int kc = 0; kc < KC; ++kc) {
        int kn = (kc + 1 < KC) ? kc + 1 : kc;         // clamped prefetch
        uint4 na  = *(const uint4*)(arow + kn * 32);
        uint4 nb0 = bwv[(t0 * KC + kn) * 64 + lane];
        uint4 nb1 = bwv[(t1 * KC + kn) * 64 + lane];
        acc0 = __builtin_amdgcn_mfma_f32_16x16x32_bf16(
                   __builtin_bit_cast(s16x8, a), __builtin_bit_cast(s16x8, b0),
                   acc0, 0, 0, 0);
        acc1 = __builtin_amdgcn_mfma_f32_16x16x32_bf16(
                   __builtin_bit_cast(s16x8, a), __builtin_bit_cast(s16x8, b1),
                   acc1, 0, 0, 0);
        a = na; b0 = nb0; b1 = nb1;
    }
    __syncthreads();          // all cbuf reads drained; smem reusable as hbuf

    // -------- Phase 3a: ReLU (bias already folded) -> hbuf ------------------
    // C/D: col = mn, row = q*4 + r   (verified mapping)
#pragma unroll
    for (int r = 0; r < 4; ++r) {
        int row = q * 4 + r;
        float v0 = acc0[r]; v0 = v0 > 0.f ? v0 : 0.f;
        float v1 = acc1[r]; v1 = v1 > 0.f ? v1 : 0.f;
        hbuf[row * HSTR + t0 * 16 + mn] = v0;   // cols >=100 are 0, never read
        hbuf[row * HSTR + t1 * 16 + mn] = v1;
    }
    __syncthreads();

    // -------- Phase 3b: fc2 (fp32 VALU) + store -----------------------------
    for (int p = tid; p < BM * 10; p += 256) {
        int mi = p / 10, o = p - mi * 10;
        const float4* hv = (const float4*)(hbuf + mi * HSTR);
        const float4* w2 = (const float4*)(W2 + (size_t)o * 100);
        float s = b2[o];
#pragma unroll
        for (int g = 0; g < 25; ++g) {
            float4 h4 = hv[g], w4 = w2[g];
            s += h4.x*w4.x + h4.y*w4.y + h4.z*w4.z + h4.w*w4.w;
        }
        out[(size_t)(m0 + mi) * 10 + o] = s;
    }
}

extern "C" void kernel_launch(void* const* d_in, const int* in_sizes, int n_in,
                              void* d_out, int out_size, void* d_ws, size_t ws_size,
                              hipStream_t stream) {
    const float* x  = (const float*)d_in[0];
    const float* cw = (const float*)d_in[1];
    const float* W1 = (const float*)d_in[2];
    const float* b1 = (const float*)d_in[3];
    const float* W2 = (const float*)d_in[4];
    const float* b2 = (const float*)d_in[5];
    float* out = (float*)d_out;
    unsigned short* bw = (unsigned short*)d_ws;    // 180,224 B used

    const int B = in_sizes[0] / 784;               // 65536

    hipLaunchKernelGGL(prep_w1, dim3((NT * KC * 64 + 255) / 256), dim3(256),
                       0, stream, W1, b1, bw);
    hipLaunchKernelGGL(digit_model_fused, dim3(B / BM), dim3(256), 0, stream,
                       x, cw, bw, W2, b2, out);
}